// Round 5
// baseline (704.175 us; speedup 1.0000x reference)
//
#include <hip/hip_runtime.h>
#include <math.h>

#define BB 64
#define NN 196
#define DD 768
#define HH 12
#define HD 64
#define MM (BB * NN)     // 12544 rows
#define WE (DD * DD)     // 589824 elements per weight matrix

typedef __attribute__((ext_vector_type(8))) short bf16x8;   // 8 bf16 = 4 VGPRs
typedef __attribute__((ext_vector_type(4))) float f32x4;

// ---- bf16 helpers (RNE, bit-level)
__device__ __forceinline__ unsigned short f2bf(float x) {
    unsigned int u = __float_as_uint(x);
    unsigned int r = (u + 0x7FFFu + ((u >> 16) & 1u)) >> 16;
    return (unsigned short)r;
}
__device__ __forceinline__ float bf2f(unsigned short b) {
    return __uint_as_float(((unsigned int)b) << 16);
}

// async global->LDS, 16B/lane; LDS dest = wave-uniform base + lane*16 (m97/m104)
__device__ __forceinline__ void gload16(const void* g, void* l) {
    __builtin_amdgcn_global_load_lds(
        (const __attribute__((address_space(1))) void*)g,
        (__attribute__((address_space(3))) void*)l, 16, 0, 0);
}

// ===========================================================================
// PATH A (preferred, needs ~156 MB ws): split-bf16 MFMA GEMMs
// ===========================================================================

__global__ __launch_bounds__(256)
void split_kernel(const float* __restrict__ src,
                  unsigned short* __restrict__ hi, unsigned short* __restrict__ lo,
                  int n4)
{
    int i = blockIdx.x * 256 + threadIdx.x;
    const int stride = gridDim.x * 256;
    for (; i < n4; i += stride) {
        const float4 v = reinterpret_cast<const float4*>(src)[i];
        ushort4 h, l;
        h.x = f2bf(v.x); l.x = f2bf(v.x - bf2f(h.x));
        h.y = f2bf(v.y); l.y = f2bf(v.y - bf2f(h.y));
        h.z = f2bf(v.z); l.z = f2bf(v.z - bf2f(h.z));
        h.w = f2bf(v.w); l.w = f2bf(v.w - bf2f(h.w));
        reinterpret_cast<ushort4*>(hi)[i] = h;
        reinterpret_cast<ushort4*>(lo)[i] = l;
    }
}

// Transpose + split weights: W [K][N] fp32 -> WT_hi/lo [N][K] bf16.
__global__ __launch_bounds__(256)
void wtrans_kernel(const float* __restrict__ W0, const float* __restrict__ W1,
                   const float* __restrict__ W2, const float* __restrict__ W3,
                   unsigned short* __restrict__ WThi, unsigned short* __restrict__ WTlo)
{
    const int w = blockIdx.z;
    const float* W = (w == 0) ? W0 : (w == 1) ? W1 : (w == 2) ? W2 : W3;
    const int kt = blockIdx.x * 32, nt = blockIdx.y * 32;

    __shared__ float tile[32][33];
    const int t = threadIdx.x;
    {
        const int r = t >> 3, c4 = (t & 7) * 4;
        const float4 v = *reinterpret_cast<const float4*>(&W[(size_t)(kt + r) * DD + nt + c4]);
        tile[r][c4 + 0] = v.x; tile[r][c4 + 1] = v.y; tile[r][c4 + 2] = v.z; tile[r][c4 + 3] = v.w;
    }
    __syncthreads();
    {
        const int n = t >> 3, k4 = (t & 7) * 4;
        ushort4 h, l;
        float x;
        x = tile[k4 + 0][n]; h.x = f2bf(x); l.x = f2bf(x - bf2f(h.x));
        x = tile[k4 + 1][n]; h.y = f2bf(x); l.y = f2bf(x - bf2f(h.y));
        x = tile[k4 + 2][n]; h.z = f2bf(x); l.z = f2bf(x - bf2f(h.z));
        x = tile[k4 + 3][n]; h.w = f2bf(x); l.w = f2bf(x - bf2f(h.w));
        const size_t off = (size_t)w * WE + (size_t)(nt + n) * DD + kt + k4;
        *reinterpret_cast<ushort4*>(&WThi[off]) = h;
        *reinterpret_cast<ushort4*>(&WTlo[off]) = l;
    }
}

// Split-bf16 MFMA GEMM: C = A@W + bias via Ah*Bh + Ah*Bl + Al*Bh (~2^-17 rel err).
// m97 structure: 128x128 tile, BK=32, 4 waves, linear LDS + global_load_lds(16B).
__global__ __launch_bounds__(256)
void gemm_mfma_kernel(const unsigned short* __restrict__ Ahi, const unsigned short* __restrict__ Alo,
                      const unsigned short* __restrict__ Wh0, const unsigned short* __restrict__ Wl0,
                      const float* __restrict__ b0, float* __restrict__ C0,
                      const unsigned short* __restrict__ Wh1, const unsigned short* __restrict__ Wl1,
                      const float* __restrict__ b1, float* __restrict__ C1,
                      const unsigned short* __restrict__ Wh2, const unsigned short* __restrict__ Wl2,
                      const float* __restrict__ b2, float* __restrict__ C2)
{
    const unsigned short* Wh; const unsigned short* Wl; const float* bias; float* C;
    const int z = blockIdx.z;
    if (z == 0)      { Wh = Wh0; Wl = Wl0; bias = b0; C = C0; }
    else if (z == 1) { Wh = Wh1; Wl = Wl1; bias = b1; C = C1; }
    else             { Wh = Wh2; Wl = Wl2; bias = b2; C = C2; }

    __shared__ unsigned short Ah[128 * 32];   // 8 KB each, linear (gload_lds dest)
    __shared__ unsigned short Al[128 * 32];
    __shared__ unsigned short Bh[128 * 32];
    __shared__ unsigned short Bl[128 * 32];

    const int tid  = threadIdx.x;
    const int lane = tid & 63;
    const int wv   = tid >> 6;
    const int wrr  = (wv >> 1) * 64;
    const int wcc  = (wv & 1) * 64;
    const int fr   = lane & 15;           // fragment row/col
    const int fg   = lane >> 4;           // k-group 0..3
    const int srow = lane >> 2;           // staging row within 16-row chunk
    const int scol = (lane & 3) * 8;      // staging k-offset (elements)

    const int row0 = blockIdx.x * 128, col0 = blockIdx.y * 128;

    f32x4 acc[4][4];
    #pragma unroll
    for (int m = 0; m < 4; ++m)
        #pragma unroll
        for (int n = 0; n < 4; ++n)
            acc[m][n] = (f32x4){0.f, 0.f, 0.f, 0.f};

    for (int k0 = 0; k0 < DD; k0 += 32) {
        #pragma unroll
        for (int cc = 0; cc < 2; ++cc) {
            const int c = wv * 2 + cc;                     // 16-row chunk 0..7
            const size_t ga = (size_t)(row0 + c * 16 + srow) * DD + k0 + scol;
            const size_t gb = (size_t)(col0 + c * 16 + srow) * DD + k0 + scol;
            gload16(Ahi + ga, &Ah[c * 512]);
            gload16(Alo + ga, &Al[c * 512]);
            gload16(Wh  + gb, &Bh[c * 512]);
            gload16(Wl  + gb, &Bl[c * 512]);
        }
        __syncthreads();   // drains vmcnt before LDS reads

        bf16x8 ah[4], al[4];
        #pragma unroll
        for (int m = 0; m < 4; ++m) {
            const int ro = (wrr + m * 16 + fr) * 32 + fg * 8;
            ah[m] = *reinterpret_cast<const bf16x8*>(&Ah[ro]);
            al[m] = *reinterpret_cast<const bf16x8*>(&Al[ro]);
        }
        #pragma unroll
        for (int n = 0; n < 4; ++n) {
            const int co = (wcc + n * 16 + fr) * 32 + fg * 8;
            const bf16x8 bh = *reinterpret_cast<const bf16x8*>(&Bh[co]);
            const bf16x8 bl = *reinterpret_cast<const bf16x8*>(&Bl[co]);
            #pragma unroll
            for (int m = 0; m < 4; ++m) {
                acc[m][n] = __builtin_amdgcn_mfma_f32_16x16x32_bf16(ah[m], bh, acc[m][n], 0, 0, 0);
                acc[m][n] = __builtin_amdgcn_mfma_f32_16x16x32_bf16(ah[m], bl, acc[m][n], 0, 0, 0);
                acc[m][n] = __builtin_amdgcn_mfma_f32_16x16x32_bf16(al[m], bh, acc[m][n], 0, 0, 0);
            }
        }
        __syncthreads();
    }

    // C/D layout: col=lane&15, row=(lane>>4)*4+reg (m89/m91)
    float bs[4];
    #pragma unroll
    for (int n = 0; n < 4; ++n) bs[n] = bias[col0 + wcc + n * 16 + fr];
    #pragma unroll
    for (int m = 0; m < 4; ++m) {
        const int rbase = row0 + wrr + m * 16 + fg * 4;
        #pragma unroll
        for (int n = 0; n < 4; ++n) {
            const int col = col0 + wcc + n * 16 + fr;
            #pragma unroll
            for (int r = 0; r < 4; ++r)
                C[(size_t)(rbase + r) * DD + col] = acc[m][n][r] + bs[n];
        }
    }
}

// ===========================================================================
// PATH B (fallback, needs ~110 MB ws): fp32 vector GEMM
// ===========================================================================
__global__ __launch_bounds__(256)
void gemm_bias_kernel(const float* __restrict__ A,
                      const float* __restrict__ W0, const float* __restrict__ b0, float* __restrict__ C0,
                      const float* __restrict__ W1, const float* __restrict__ b1, float* __restrict__ C1,
                      const float* __restrict__ W2, const float* __restrict__ b2, float* __restrict__ C2)
{
    const int K = DD, Nc = DD;
    const float* W; const float* bias; float* C;
    const int z = blockIdx.z;
    if (z == 0)      { W = W0; bias = b0; C = C0; }
    else if (z == 1) { W = W1; bias = b1; C = C1; }
    else             { W = W2; bias = b2; C = C2; }

    __shared__ float As[16][132];
    __shared__ float Bs[16][132];

    const int tid = threadIdx.x;
    const int tx = tid & 15, ty = tid >> 4;
    const int row0 = blockIdx.x * 128, col0 = blockIdx.y * 128;

    float acc[8][8];
    #pragma unroll
    for (int i = 0; i < 8; ++i)
        #pragma unroll
        for (int j = 0; j < 8; ++j) acc[i][j] = 0.f;

    for (int k0 = 0; k0 < K; k0 += 16) {
        #pragma unroll
        for (int l = 0; l < 2; ++l) {
            const int f = tid + l * 256;
            const int r = f >> 2, c4 = (f & 3) << 2;
            const float4 av = *reinterpret_cast<const float4*>(&A[(size_t)(row0 + r) * K + k0 + c4]);
            As[c4 + 0][r] = av.x; As[c4 + 1][r] = av.y; As[c4 + 2][r] = av.z; As[c4 + 3][r] = av.w;
            const int rb = f >> 5, cb = (f & 31) << 2;
            *reinterpret_cast<float4*>(&Bs[rb][cb]) =
                *reinterpret_cast<const float4*>(&W[(size_t)(k0 + rb) * Nc + col0 + cb]);
        }
        __syncthreads();
        #pragma unroll
        for (int kk = 0; kk < 16; ++kk) {
            float a[8], bv[8];
            *reinterpret_cast<float4*>(&a[0])  = *reinterpret_cast<float4*>(&As[kk][ty * 4]);
            *reinterpret_cast<float4*>(&a[4])  = *reinterpret_cast<float4*>(&As[kk][64 + ty * 4]);
            *reinterpret_cast<float4*>(&bv[0]) = *reinterpret_cast<float4*>(&Bs[kk][tx * 4]);
            *reinterpret_cast<float4*>(&bv[4]) = *reinterpret_cast<float4*>(&Bs[kk][64 + tx * 4]);
            #pragma unroll
            for (int i = 0; i < 8; ++i)
                #pragma unroll
                for (int j = 0; j < 8; ++j)
                    acc[i][j] = fmaf(a[i], bv[j], acc[i][j]);
        }
        __syncthreads();
    }

    #pragma unroll
    for (int i = 0; i < 8; ++i) {
        const int r = row0 + ((i < 4) ? (ty * 4 + i) : (64 + ty * 4 + (i - 4)));
        #pragma unroll
        for (int jh = 0; jh < 2; ++jh) {
            const int c = col0 + jh * 64 + tx * 4;
            float4 o;
            o.x = acc[i][jh * 4 + 0] + bias[c + 0];
            o.y = acc[i][jh * 4 + 1] + bias[c + 1];
            o.z = acc[i][jh * 4 + 2] + bias[c + 2];
            o.w = acc[i][jh * 4 + 3] + bias[c + 3];
            *reinterpret_cast<float4*>(&C[(size_t)r * Nc + c]) = o;
        }
    }
}

// ===========================================================================
// Attention (both paths): one block per (h,b); K,V in LDS; 1 thread/query;
// online softmax + deferred rescale. BF16OUT: ctx -> bf16 hi/lo (MFMA path);
// else ctx -> fp32 written over the V buffer (vector path; V LDS-resident
// before writes, per-(b,h) regions disjoint).
// ===========================================================================
template <bool BF16OUT>
__global__ __launch_bounds__(256, 1)
void stoch_attn_kernel(const float* __restrict__ q,
                       const float* __restrict__ k,
                       float* __restrict__ v,
                       unsigned short* __restrict__ ctxhi,
                       unsigned short* __restrict__ ctxlo,
                       const float* __restrict__ Wsig,
                       const float* __restrict__ bsig,
                       const float* __restrict__ temp)
{
    const int h = blockIdx.x;
    const int b = blockIdx.y;

    __shared__ float Ks[NN][68];
    __shared__ float Vs[NN][68];

    const int tid = threadIdx.x;
    const size_t head_off = ((size_t)b * NN) * DD + (size_t)h * HD;

    for (int f = tid; f < NN * 16; f += 256) {
        const int n = f >> 4, c = (f & 15) << 2;
        *reinterpret_cast<float4*>(&Ks[n][c]) =
            *reinterpret_cast<const float4*>(&k[head_off + (size_t)n * DD + c]);
        *reinterpret_cast<float4*>(&Vs[n][c]) =
            *reinterpret_cast<const float4*>(&v[head_off + (size_t)n * DD + c]);
    }
    __syncthreads();

    const int n = tid;
    if (n < NN) {
        const float* qrow = q + head_off + (size_t)n * DD;
        float qreg[64];
        #pragma unroll
        for (int d4 = 0; d4 < 16; ++d4)
            *reinterpret_cast<float4*>(&qreg[d4 * 4]) =
                *reinterpret_cast<const float4*>(&qrow[d4 * 4]);

        float sd = 0.f;
        #pragma unroll
        for (int d = 0; d < 64; ++d) sd = fmaf(qreg[d], Wsig[d], sd);
        sd += bsig[0];
        const float sp = fmaxf(sd, 0.f) + log1pf(expf(-fabsf(sd)));
        const float st = (sp + 1e-3f) * temp[0];
        const float inv_denom = 1.0f / (2.0f * st * st);

        const int ry = n / 14, rx = n - 14 * (n / 14);

        float ctx[64];
        #pragma unroll
        for (int d = 0; d < 64; ++d) ctx[d] = 0.f;
        float mcur = 0.f, ssum = 0.f;

        int jy = 0, jx = 0;
        for (int j = 0; j < NN; ++j) {
            float s0 = 0.f, s1 = 0.f, s2 = 0.f, s3 = 0.f;
            #pragma unroll
            for (int d4 = 0; d4 < 16; ++d4) {
                const float4 kv = *reinterpret_cast<const float4*>(&Ks[j][d4 * 4]);
                s0 = fmaf(qreg[d4 * 4 + 0], kv.x, s0);
                s1 = fmaf(qreg[d4 * 4 + 1], kv.y, s1);
                s2 = fmaf(qreg[d4 * 4 + 2], kv.z, s2);
                s3 = fmaf(qreg[d4 * 4 + 3], kv.w, s3);
            }
            const float s = ((s0 + s1) + (s2 + s3)) * 0.125f;
            const int idy = ry - jy, idx = rx - jx;
            const float d2 = (float)(idy * idy + idx * idx);
            const float val = expf(-d2 * inv_denom) * s;
            if (val > mcur + 8.0f) {                // deferred rescale (T13)
                const float scale = expf(mcur - val);
                ssum *= scale;
                #pragma unroll
                for (int d = 0; d < 64; ++d) ctx[d] *= scale;
                mcur = val;
            }
            const float p = expf(val - mcur);
            ssum += p;
            #pragma unroll
            for (int d4 = 0; d4 < 16; ++d4) {
                const float4 vv = *reinterpret_cast<const float4*>(&Vs[j][d4 * 4]);
                ctx[d4 * 4 + 0] = fmaf(p, vv.x, ctx[d4 * 4 + 0]);
                ctx[d4 * 4 + 1] = fmaf(p, vv.y, ctx[d4 * 4 + 1]);
                ctx[d4 * 4 + 2] = fmaf(p, vv.z, ctx[d4 * 4 + 2]);
                ctx[d4 * 4 + 3] = fmaf(p, vv.w, ctx[d4 * 4 + 3]);
            }
            if (++jx == 14) { jx = 0; ++jy; }
        }

        const float inv = 1.0f / ssum;
        const size_t obase = head_off + (size_t)n * DD;
        if (BF16OUT) {
            #pragma unroll
            for (int d4 = 0; d4 < 16; ++d4) {
                ushort4 h4, l4;
                float x;
                x = ctx[d4 * 4 + 0] * inv; h4.x = f2bf(x); l4.x = f2bf(x - bf2f(h4.x));
                x = ctx[d4 * 4 + 1] * inv; h4.y = f2bf(x); l4.y = f2bf(x - bf2f(h4.y));
                x = ctx[d4 * 4 + 2] * inv; h4.z = f2bf(x); l4.z = f2bf(x - bf2f(h4.z));
                x = ctx[d4 * 4 + 3] * inv; h4.w = f2bf(x); l4.w = f2bf(x - bf2f(h4.w));
                *reinterpret_cast<ushort4*>(&ctxhi[obase + d4 * 4]) = h4;
                *reinterpret_cast<ushort4*>(&ctxlo[obase + d4 * 4]) = l4;
            }
        } else {
            #pragma unroll
            for (int d4 = 0; d4 < 16; ++d4) {
                float4 o;
                o.x = ctx[d4 * 4 + 0] * inv;
                o.y = ctx[d4 * 4 + 1] * inv;
                o.z = ctx[d4 * 4 + 2] * inv;
                o.w = ctx[d4 * 4 + 3] * inv;
                *reinterpret_cast<float4*>(&v[obase + d4 * 4]) = o;  // overwrite V
            }
        }
    }
}

// ---------------------------------------------------------------------------
extern "C" void kernel_launch(void* const* d_in, const int* in_sizes, int n_in,
                              void* d_out, int out_size, void* d_ws, size_t ws_size,
                              hipStream_t stream) {
    const float* hidden = (const float*)d_in[0];
    const float* temp   = (const float*)d_in[1];
    const float* Wq     = (const float*)d_in[2];
    const float* bq     = (const float*)d_in[3];
    const float* Wk     = (const float*)d_in[4];
    const float* bk     = (const float*)d_in[5];
    const float* Wv     = (const float*)d_in[6];
    const float* bv     = (const float*)d_in[7];
    const float* Wo     = (const float*)d_in[8];
    const float* bo     = (const float*)d_in[9];
    const float* Wsig   = (const float*)d_in[10];
    const float* bsig   = (const float*)d_in[11];
    float* out = (float*)d_out;

    const size_t A_ELEMS = (size_t)MM * DD;        // 9,633,792
    const size_t REQ_MFMA = A_ELEMS * 2 * 2        // Ahi/Alo (bf16)
                          + (size_t)4 * WE * 2 * 2 // WThi/WTlo (4 weights)
                          + A_ELEMS * 4 * 3;       // q/k/v fp32  => ~156 MB

    if (ws_size >= REQ_MFMA) {
        // ---------- PATH A: split-bf16 MFMA ----------
        unsigned char* p = (unsigned char*)d_ws;
        unsigned short* Ahi  = (unsigned short*)p; p += A_ELEMS * 2;
        unsigned short* Alo  = (unsigned short*)p; p += A_ELEMS * 2;
        unsigned short* WThi = (unsigned short*)p; p += (size_t)4 * WE * 2;
        unsigned short* WTlo = (unsigned short*)p; p += (size_t)4 * WE * 2;
        float* qbuf = (float*)p; p += A_ELEMS * 4;
        float* kbuf = (float*)p; p += A_ELEMS * 4;
        float* vbuf = (float*)p;
        // ctx aliases Ahi/Alo (dead after QKV GEMM; stream-ordered)
        unsigned short* ctxhi = Ahi;
        unsigned short* ctxlo = Alo;

        split_kernel<<<2048, 256, 0, stream>>>(hidden, Ahi, Alo, (int)(A_ELEMS / 4));
        wtrans_kernel<<<dim3(24, 24, 4), 256, 0, stream>>>(Wq, Wk, Wv, Wo, WThi, WTlo);

        gemm_mfma_kernel<<<dim3(MM / 128, DD / 128, 3), 256, 0, stream>>>(
            Ahi, Alo,
            WThi + 0 * (size_t)WE, WTlo + 0 * (size_t)WE, bq, qbuf,
            WThi + 1 * (size_t)WE, WTlo + 1 * (size_t)WE, bk, kbuf,
            WThi + 2 * (size_t)WE, WTlo + 2 * (size_t)WE, bv, vbuf);

        stoch_attn_kernel<true><<<dim3(HH, BB), 256, 0, stream>>>(
            qbuf, kbuf, vbuf, ctxhi, ctxlo, Wsig, bsig, temp);

        gemm_mfma_kernel<<<dim3(MM / 128, DD / 128, 1), 256, 0, stream>>>(
            ctxhi, ctxlo,
            WThi + 3 * (size_t)WE, WTlo + 3 * (size_t)WE, bo, out,
            WThi + 3 * (size_t)WE, WTlo + 3 * (size_t)WE, bo, out,
            WThi + 3 * (size_t)WE, WTlo + 3 * (size_t)WE, bo, out);
    } else {
        // ---------- PATH B: fp32 vector (needs only q/k/v = ~110 MB) ----------
        float* qbuf = (float*)d_ws;
        float* kbuf = qbuf + A_ELEMS;
        float* vbuf = kbuf + A_ELEMS;   // ctx overwrites vbuf

        dim3 g1(MM / 128, DD / 128, 3);
        gemm_bias_kernel<<<g1, 256, 0, stream>>>(hidden,
                                                 Wq, bq, qbuf,
                                                 Wk, bk, kbuf,
                                                 Wv, bv, vbuf);

        stoch_attn_kernel<false><<<dim3(HH, BB), 256, 0, stream>>>(
            qbuf, kbuf, vbuf, nullptr, nullptr, Wsig, bsig, temp);

        dim3 g3(MM / 128, DD / 128, 1);
        gemm_bias_kernel<<<g3, 256, 0, stream>>>(vbuf,
                                                 Wo, bo, out,
                                                 Wo, bo, out,
                                                 Wo, bo, out);
    }
}

// Round 10
// 456.141 us; speedup vs baseline: 1.5438x; 1.5438x over previous
//
#include <hip/hip_runtime.h>
#include <math.h>

#define BB 64
#define NN 196
#define DD 768
#define HH 12
#define HD 64
#define MM (BB * NN)     // 12544 rows
#define WE (DD * DD)     // 589824 elements per weight matrix

typedef __attribute__((ext_vector_type(8))) short bf16x8;   // 8 bf16 = 4 VGPRs
typedef __attribute__((ext_vector_type(4))) float f32x4;

// ---- bf16 helpers (RNE, bit-level)
__device__ __forceinline__ unsigned short f2bf(float x) {
    unsigned int u = __float_as_uint(x);
    unsigned int r = (u + 0x7FFFu + ((u >> 16) & 1u)) >> 16;
    return (unsigned short)r;
}
__device__ __forceinline__ float bf2f(unsigned short b) {
    return __uint_as_float(((unsigned int)b) << 16);
}

// async global->LDS, 16B/lane; LDS dest = wave-uniform base + lane*16 (m97/m104)
__device__ __forceinline__ void gload16(const void* g, void* l) {
    __builtin_amdgcn_global_load_lds(
        (const __attribute__((address_space(1))) void*)g,
        (__attribute__((address_space(3))) void*)l, 16, 0, 0);
}

// ===========================================================================
// Prep kernels (HW-validated round 5)
// ===========================================================================

__global__ __launch_bounds__(256)
void split_kernel(const float* __restrict__ src,
                  unsigned short* __restrict__ hi, unsigned short* __restrict__ lo,
                  int n4)
{
    int i = blockIdx.x * 256 + threadIdx.x;
    const int stride = gridDim.x * 256;
    for (; i < n4; i += stride) {
        const float4 v = reinterpret_cast<const float4*>(src)[i];
        ushort4 h, l;
        h.x = f2bf(v.x); l.x = f2bf(v.x - bf2f(h.x));
        h.y = f2bf(v.y); l.y = f2bf(v.y - bf2f(h.y));
        h.z = f2bf(v.z); l.z = f2bf(v.z - bf2f(h.z));
        h.w = f2bf(v.w); l.w = f2bf(v.w - bf2f(h.w));
        reinterpret_cast<ushort4*>(hi)[i] = h;
        reinterpret_cast<ushort4*>(lo)[i] = l;
    }
}

__global__ __launch_bounds__(256)
void wtrans_kernel(const float* __restrict__ W0, const float* __restrict__ W1,
                   const float* __restrict__ W2, const float* __restrict__ W3,
                   unsigned short* __restrict__ WThi, unsigned short* __restrict__ WTlo)
{
    const int w = blockIdx.z;
    const float* W = (w == 0) ? W0 : (w == 1) ? W1 : (w == 2) ? W2 : W3;
    const int kt = blockIdx.x * 32, nt = blockIdx.y * 32;

    __shared__ float tile[32][33];
    const int t = threadIdx.x;
    {
        const int r = t >> 3, c4 = (t & 7) * 4;
        const float4 v = *reinterpret_cast<const float4*>(&W[(size_t)(kt + r) * DD + nt + c4]);
        tile[r][c4 + 0] = v.x; tile[r][c4 + 1] = v.y; tile[r][c4 + 2] = v.z; tile[r][c4 + 3] = v.w;
    }
    __syncthreads();
    {
        const int n = t >> 3, k4 = (t & 7) * 4;
        ushort4 h, l;
        float x;
        x = tile[k4 + 0][n]; h.x = f2bf(x); l.x = f2bf(x - bf2f(h.x));
        x = tile[k4 + 1][n]; h.y = f2bf(x); l.y = f2bf(x - bf2f(h.y));
        x = tile[k4 + 2][n]; h.z = f2bf(x); l.z = f2bf(x - bf2f(h.z));
        x = tile[k4 + 3][n]; h.w = f2bf(x); l.w = f2bf(x - bf2f(h.w));
        const size_t off = (size_t)w * WE + (size_t)(nt + n) * DD + kt + k4;
        *reinterpret_cast<ushort4*>(&WThi[off]) = h;
        *reinterpret_cast<ushort4*>(&WTlo[off]) = l;
    }
}

// ===========================================================================
// Split-bf16 MFMA GEMM (HW-validated round 5)
// ===========================================================================
__global__ __launch_bounds__(256)
void gemm_mfma_kernel(const unsigned short* __restrict__ Ahi, const unsigned short* __restrict__ Alo,
                      const unsigned short* __restrict__ Wh0, const unsigned short* __restrict__ Wl0,
                      const float* __restrict__ b0, float* __restrict__ C0,
                      const unsigned short* __restrict__ Wh1, const unsigned short* __restrict__ Wl1,
                      const float* __restrict__ b1, float* __restrict__ C1,
                      const unsigned short* __restrict__ Wh2, const unsigned short* __restrict__ Wl2,
                      const float* __restrict__ b2, float* __restrict__ C2)
{
    const unsigned short* Wh; const unsigned short* Wl; const float* bias; float* C;
    const int z = blockIdx.z;
    if (z == 0)      { Wh = Wh0; Wl = Wl0; bias = b0; C = C0; }
    else if (z == 1) { Wh = Wh1; Wl = Wl1; bias = b1; C = C1; }
    else             { Wh = Wh2; Wl = Wl2; bias = b2; C = C2; }

    __shared__ unsigned short Ah[128 * 32];
    __shared__ unsigned short Al[128 * 32];
    __shared__ unsigned short Bh[128 * 32];
    __shared__ unsigned short Bl[128 * 32];

    const int tid  = threadIdx.x;
    const int lane = tid & 63;
    const int wv   = tid >> 6;
    const int wrr  = (wv >> 1) * 64;
    const int wcc  = (wv & 1) * 64;
    const int fr   = lane & 15;
    const int fg   = lane >> 4;
    const int srow = lane >> 2;
    const int scol = (lane & 3) * 8;

    const int row0 = blockIdx.x * 128, col0 = blockIdx.y * 128;

    f32x4 acc[4][4];
    #pragma unroll
    for (int m = 0; m < 4; ++m)
        #pragma unroll
        for (int n = 0; n < 4; ++n)
            acc[m][n] = (f32x4){0.f, 0.f, 0.f, 0.f};

    for (int k0 = 0; k0 < DD; k0 += 32) {
        #pragma unroll
        for (int cc = 0; cc < 2; ++cc) {
            const int c = wv * 2 + cc;
            const size_t ga = (size_t)(row0 + c * 16 + srow) * DD + k0 + scol;
            const size_t gb = (size_t)(col0 + c * 16 + srow) * DD + k0 + scol;
            gload16(Ahi + ga, &Ah[c * 512]);
            gload16(Alo + ga, &Al[c * 512]);
            gload16(Wh  + gb, &Bh[c * 512]);
            gload16(Wl  + gb, &Bl[c * 512]);
        }
        __syncthreads();

        bf16x8 ah[4], al[4];
        #pragma unroll
        for (int m = 0; m < 4; ++m) {
            const int ro = (wrr + m * 16 + fr) * 32 + fg * 8;
            ah[m] = *reinterpret_cast<const bf16x8*>(&Ah[ro]);
            al[m] = *reinterpret_cast<const bf16x8*>(&Al[ro]);
        }
        #pragma unroll
        for (int n = 0; n < 4; ++n) {
            const int co = (wcc + n * 16 + fr) * 32 + fg * 8;
            const bf16x8 bh = *reinterpret_cast<const bf16x8*>(&Bh[co]);
            const bf16x8 bl = *reinterpret_cast<const bf16x8*>(&Bl[co]);
            #pragma unroll
            for (int m = 0; m < 4; ++m) {
                acc[m][n] = __builtin_amdgcn_mfma_f32_16x16x32_bf16(ah[m], bh, acc[m][n], 0, 0, 0);
                acc[m][n] = __builtin_amdgcn_mfma_f32_16x16x32_bf16(ah[m], bl, acc[m][n], 0, 0, 0);
                acc[m][n] = __builtin_amdgcn_mfma_f32_16x16x32_bf16(al[m], bh, acc[m][n], 0, 0, 0);
            }
        }
        __syncthreads();
    }

    float bs[4];
    #pragma unroll
    for (int n = 0; n < 4; ++n) bs[n] = bias[col0 + wcc + n * 16 + fr];
    #pragma unroll
    for (int m = 0; m < 4; ++m) {
        const int rbase = row0 + wrr + m * 16 + fg * 4;
        #pragma unroll
        for (int n = 0; n < 4; ++n) {
            const int col = col0 + wcc + n * 16 + fr;
            #pragma unroll
            for (int r = 0; r < 4; ++r)
                C[(size_t)(rbase + r) * DD + col] = acc[m][n][r] + bs[n];
        }
    }
}

// ===========================================================================
// MFMA attention: one block per (h,b), 4 waves. Swapped QK^T (mfma(K,Q) ->
// lane holds all keys of ONE query col q=l&15 -> softmax = in-lane reduce +
// shfl_xor(16,32)). Split-bf16 S and PV (~2^-17). P relayout via per-wave
// 32-key LDS chunk (wave-private, in-order LDS, no barrier). V^T staged at
// block start (rows padded to 232 -> 2-way-free b128 reads). K as 2x32-wide
// blocks (the GEMM-proven stride). Fragment maps = HW-validated round 5.
// ===========================================================================
__global__ __launch_bounds__(256, 1)
void stoch_attn_mfma(const float* __restrict__ q,
                     const float* __restrict__ k,
                     const float* __restrict__ v,
                     unsigned short* __restrict__ ctxhi,
                     unsigned short* __restrict__ ctxlo,
                     const float* __restrict__ Wsig,
                     const float* __restrict__ bsig,
                     const float* __restrict__ temp)
{
    __shared__ unsigned short Khi[2][208][32];   // 26.0 KB
    __shared__ unsigned short Klo[2][208][32];   // 26.0 KB
    __shared__ unsigned short VThi[64][232];     // 29.0 KB (cols 196..231 zeroed)
    __shared__ unsigned short VTlo[64][232];     // 29.0 KB
    __shared__ unsigned short PwH[4][16][40];    // 5.0 KB (per-wave 32-key P chunk)
    __shared__ unsigned short PwL[4][16][40];    // 5.0 KB
    __shared__ float invd[208];                  // 0.8 KB   => ~120.9 KB total

    const int h = blockIdx.x;
    const int b = blockIdx.y;
    const int tid = threadIdx.x;

    const size_t head_off = ((size_t)b * NN) * DD + (size_t)h * HD;
    const float* kbase = k + head_off;
    const float* vbase = v + head_off;
    const float* qbase = q + head_off;

    // ---- stage K -> Khi/Klo [2][208][32] (rows >=196 left junk; guarded later)
    for (int i = tid; i < NN * 16; i += 256) {
        const int n = i >> 4, c4 = (i & 15) * 4;
        const float4 kv = *reinterpret_cast<const float4*>(&kbase[(size_t)n * DD + c4]);
        const int kb = c4 >> 5, cc = c4 & 31;
        ushort4 hh, ll;
        hh.x = f2bf(kv.x); ll.x = f2bf(kv.x - bf2f(hh.x));
        hh.y = f2bf(kv.y); ll.y = f2bf(kv.y - bf2f(hh.y));
        hh.z = f2bf(kv.z); ll.z = f2bf(kv.z - bf2f(hh.z));
        hh.w = f2bf(kv.w); ll.w = f2bf(kv.w - bf2f(hh.w));
        *reinterpret_cast<ushort4*>(&Khi[kb][n][cc]) = hh;
        *reinterpret_cast<ushort4*>(&Klo[kb][n][cc]) = ll;
    }

    // ---- stage V^T -> VThi/VTlo [64][232]; lane=d so global reads coalesce
    {
        const int d = tid & 63, qtr = tid >> 6;
        for (int j2 = qtr; j2 < 98; j2 += 4) {
            const float v0 = vbase[(size_t)(2 * j2) * DD + d];
            const float v1 = vbase[(size_t)(2 * j2 + 1) * DD + d];
            const unsigned short h0 = f2bf(v0), h1 = f2bf(v1);
            const unsigned short l0 = f2bf(v0 - bf2f(h0)), l1 = f2bf(v1 - bf2f(h1));
            *reinterpret_cast<unsigned int*>(&VThi[d][2 * j2]) = (unsigned)h0 | ((unsigned)h1 << 16);
            *reinterpret_cast<unsigned int*>(&VTlo[d][2 * j2]) = (unsigned)l0 | ((unsigned)l1 << 16);
        }
        for (int c = 98 + qtr; c < 116; c += 4) {   // zero pad cols 196..231
            *reinterpret_cast<unsigned int*>(&VThi[d][2 * c]) = 0u;
            *reinterpret_cast<unsigned int*>(&VTlo[d][2 * c]) = 0u;
        }
    }

    // ---- per-query 1/(2*(sigma*T)^2)
    if (tid < 208) {
        const int n = (tid < NN) ? tid : (NN - 1);
        const float* qr = qbase + (size_t)n * DD;
        float sd = 0.f;
        for (int d = 0; d < 64; ++d) sd = fmaf(qr[d], Wsig[d], sd);
        sd += bsig[0];
        const float sp = fmaxf(sd, 0.f) + log1pf(expf(-fabsf(sd)));
        const float st = (sp + 1e-3f) * temp[0];
        invd[tid] = 1.0f / (2.0f * st * st);
    }
    __syncthreads();

    const int wv = tid >> 6, lane = tid & 63;
    const int fr = lane & 15, fg = lane >> 4;
    unsigned short* pwh = &PwH[wv][0][0];
    unsigned short* pwl = &PwL[wv][0][0];

    for (int qt = wv; qt < 13; qt += 4) {
        // ---- Q fragments from global (fp32 -> split bf16), row clamped
        int nq = qt * 16 + fr; if (nq > NN - 1) nq = NN - 1;
        const float* qrow = qbase + (size_t)nq * DD;
        bf16x8 qh[2], ql[2];
        #pragma unroll
        for (int kb = 0; kb < 2; ++kb) {
            const float4 a0 = *reinterpret_cast<const float4*>(&qrow[kb * 32 + fg * 8]);
            const float4 a1 = *reinterpret_cast<const float4*>(&qrow[kb * 32 + fg * 8 + 4]);
            const float xs[8] = {a0.x, a0.y, a0.z, a0.w, a1.x, a1.y, a1.z, a1.w};
            bf16x8 th, tl;
            #pragma unroll
            for (int e = 0; e < 8; ++e) {
                const unsigned short hh = f2bf(xs[e]);
                th[e] = (short)hh;
                tl[e] = (short)f2bf(xs[e] - bf2f(hh));
            }
            qh[kb] = th; ql[kb] = tl;
        }

        // ---- QK^T (swapped): accS[kt] = S^T tile; lane: q=fr, k=fg*4+r
        f32x4 accS[13];
        #pragma unroll
        for (int kt = 0; kt < 13; ++kt) {
            f32x4 a4 = (f32x4){0.f, 0.f, 0.f, 0.f};
            #pragma unroll
            for (int kb = 0; kb < 2; ++kb) {
                const bf16x8 kh = *reinterpret_cast<const bf16x8*>(&Khi[kb][kt * 16 + fr][fg * 8]);
                const bf16x8 kl = *reinterpret_cast<const bf16x8*>(&Klo[kb][kt * 16 + fr][fg * 8]);
                a4 = __builtin_amdgcn_mfma_f32_16x16x32_bf16(kh, qh[kb], a4, 0, 0, 0);
                a4 = __builtin_amdgcn_mfma_f32_16x16x32_bf16(kh, ql[kb], a4, 0, 0, 0);
                a4 = __builtin_amdgcn_mfma_f32_16x16x32_bf16(kl, qh[kb], a4, 0, 0, 0);
            }
            accS[kt] = a4;
        }

        // ---- gaussian mask + full-row softmax (q = fr)
        const float idq = invd[qt * 16 + fr];
        const int nqr = qt * 16 + fr;
        const int ry = (nqr * 586) >> 13;
        const int rx = nqr - 14 * ry;

        float m = -1e30f;
        #pragma unroll
        for (int kt = 0; kt < 13; ++kt) {
            #pragma unroll
            for (int r = 0; r < 4; ++r) {
                const int j = kt * 16 + fg * 4 + r;
                const int jy = (j * 586) >> 13;
                const int jx = j - 14 * jy;
                const float d2 = (float)((ry - jy) * (ry - jy) + (rx - jx) * (rx - jx));
                const float msk = __expf(-d2 * idq);
                const float val = (j < NN) ? msk * accS[kt][r] * 0.125f : -1e30f;
                accS[kt][r] = val;
                m = fmaxf(m, val);
            }
        }
        m = fmaxf(m, __shfl_xor(m, 16));
        m = fmaxf(m, __shfl_xor(m, 32));

        float ssum = 0.f;
        #pragma unroll
        for (int kt = 0; kt < 13; ++kt) {
            #pragma unroll
            for (int r = 0; r < 4; ++r) {
                const float p = __expf(accS[kt][r] - m);
                accS[kt][r] = p;
                ssum += p;
            }
        }
        ssum += __shfl_xor(ssum, 16);
        ssum += __shfl_xor(ssum, 32);
        const float inv = 1.0f / ssum;

        // ---- PV: per 32-key block, relayout P via wave-private LDS chunk
        f32x4 acc[4];
        #pragma unroll
        for (int dt = 0; dt < 4; ++dt) acc[dt] = (f32x4){0.f, 0.f, 0.f, 0.f};

        #pragma unroll
        for (int kb2 = 0; kb2 < 7; ++kb2) {
            #pragma unroll
            for (int slot = 0; slot < 2; ++slot) {
                const int kt = 2 * kb2 + slot;
                unsigned int h01, h23, l01, l23;
                if (kt < 13) {
                    const float p0 = accS[kt][0] * inv, p1 = accS[kt][1] * inv;
                    const float p2 = accS[kt][2] * inv, p3 = accS[kt][3] * inv;
                    const unsigned short ph0 = f2bf(p0), ph1 = f2bf(p1), ph2 = f2bf(p2), ph3 = f2bf(p3);
                    const unsigned short pl0 = f2bf(p0 - bf2f(ph0)), pl1 = f2bf(p1 - bf2f(ph1));
                    const unsigned short pl2 = f2bf(p2 - bf2f(ph2)), pl3 = f2bf(p3 - bf2f(ph3));
                    h01 = (unsigned)ph0 | ((unsigned)ph1 << 16);
                    h23 = (unsigned)ph2 | ((unsigned)ph3 << 16);
                    l01 = (unsigned)pl0 | ((unsigned)pl1 << 16);
                    l23 = (unsigned)pl2 | ((unsigned)pl3 << 16);
                } else {
                    h01 = h23 = l01 = l23 = 0u;
                }
                const unsigned int uidx = (unsigned)(fr * 20 + slot * 8 + fg * 2);
                reinterpret_cast<unsigned int*>(pwh)[uidx + 0] = h01;
                reinterpret_cast<unsigned int*>(pwh)[uidx + 1] = h23;
                reinterpret_cast<unsigned int*>(pwl)[uidx + 0] = l01;
                reinterpret_cast<unsigned int*>(pwl)[uidx + 1] = l23;
            }
            // wave-private LDS: in-order within wave; compiler inserts lgkm waits
            const bf16x8 pfh = *reinterpret_cast<const bf16x8*>(&pwh[fr * 40 + fg * 8]);
            const bf16x8 pfl = *reinterpret_cast<const bf16x8*>(&pwl[fr * 40 + fg * 8]);
            #pragma unroll
            for (int dt = 0; dt < 4; ++dt) {
                const bf16x8 vh = *reinterpret_cast<const bf16x8*>(&VThi[dt * 16 + fr][kb2 * 32 + fg * 8]);
                const bf16x8 vl = *reinterpret_cast<const bf16x8*>(&VTlo[dt * 16 + fr][kb2 * 32 + fg * 8]);
                acc[dt] = __builtin_amdgcn_mfma_f32_16x16x32_bf16(pfh, vh, acc[dt], 0, 0, 0);
                acc[dt] = __builtin_amdgcn_mfma_f32_16x16x32_bf16(pfh, vl, acc[dt], 0, 0, 0);
                acc[dt] = __builtin_amdgcn_mfma_f32_16x16x32_bf16(pfl, vh, acc[dt], 0, 0, 0);
            }
        }

        // ---- store ctx (C/D: q = fg*4+r, d = fr) as bf16 hi/lo
        #pragma unroll
        for (int dt = 0; dt < 4; ++dt) {
            #pragma unroll
            for (int r = 0; r < 4; ++r) {
                const int n = qt * 16 + fg * 4 + r;
                if (n < NN) {
                    const float x = acc[dt][r];
                    const unsigned short xh = f2bf(x);
                    const unsigned short xl = f2bf(x - bf2f(xh));
                    const size_t off = ((size_t)(b * NN + n)) * DD + h * HD + dt * 16 + fr;
                    ctxhi[off] = xh;
                    ctxlo[off] = xl;
                }
            }
        }
    }
}

// ===========================================================================
// PATH B fallback pieces (fp32 vector GEMM + scalar attention)
// ===========================================================================
__global__ __launch_bounds__(256)
void gemm_bias_kernel(const float* __restrict__ A,
                      const float* __restrict__ W0, const float* __restrict__ b0, float* __restrict__ C0,
                      const float* __restrict__ W1, const float* __restrict__ b1, float* __restrict__ C1,
                      const float* __restrict__ W2, const float* __restrict__ b2, float* __restrict__ C2)
{
    const int K = DD, Nc = DD;
    const float* W; const float* bias; float* C;
    const int z = blockIdx.z;
    if (z == 0)      { W = W0; bias = b0; C = C0; }
    else if (z == 1) { W = W1; bias = b1; C = C1; }
    else             { W = W2; bias = b2; C = C2; }

    __shared__ float As[16][132];
    __shared__ float Bs[16][132];

    const int tid = threadIdx.x;
    const int tx = tid & 15, ty = tid >> 4;
    const int row0 = blockIdx.x * 128, col0 = blockIdx.y * 128;

    float acc[8][8];
    #pragma unroll
    for (int i = 0; i < 8; ++i)
        #pragma unroll
        for (int j = 0; j < 8; ++j) acc[i][j] = 0.f;

    for (int k0 = 0; k0 < K; k0 += 16) {
        #pragma unroll
        for (int l = 0; l < 2; ++l) {
            const int f = tid + l * 256;
            const int r = f >> 2, c4 = (f & 3) << 2;
            const float4 av = *reinterpret_cast<const float4*>(&A[(size_t)(row0 + r) * K + k0 + c4]);
            As[c4 + 0][r] = av.x; As[c4 + 1][r] = av.y; As[c4 + 2][r] = av.z; As[c4 + 3][r] = av.w;
            const int rb = f >> 5, cb = (f & 31) << 2;
            *reinterpret_cast<float4*>(&Bs[rb][cb]) =
                *reinterpret_cast<const float4*>(&W[(size_t)(k0 + rb) * Nc + col0 + cb]);
        }
        __syncthreads();
        #pragma unroll
        for (int kk = 0; kk < 16; ++kk) {
            float a[8], bv[8];
            *reinterpret_cast<float4*>(&a[0])  = *reinterpret_cast<float4*>(&As[kk][ty * 4]);
            *reinterpret_cast<float4*>(&a[4])  = *reinterpret_cast<float4*>(&As[kk][64 + ty * 4]);
            *reinterpret_cast<float4*>(&bv[0]) = *reinterpret_cast<float4*>(&Bs[kk][tx * 4]);
            *reinterpret_cast<float4*>(&bv[4]) = *reinterpret_cast<float4*>(&Bs[kk][64 + tx * 4]);
            #pragma unroll
            for (int i = 0; i < 8; ++i)
                #pragma unroll
                for (int j = 0; j < 8; ++j)
                    acc[i][j] = fmaf(a[i], bv[j], acc[i][j]);
        }
        __syncthreads();
    }

    #pragma unroll
    for (int i = 0; i < 8; ++i) {
        const int r = row0 + ((i < 4) ? (ty * 4 + i) : (64 + ty * 4 + (i - 4)));
        #pragma unroll
        for (int jh = 0; jh < 2; ++jh) {
            const int c = col0 + jh * 64 + tx * 4;
            float4 o;
            o.x = acc[i][jh * 4 + 0] + bias[c + 0];
            o.y = acc[i][jh * 4 + 1] + bias[c + 1];
            o.z = acc[i][jh * 4 + 2] + bias[c + 2];
            o.w = acc[i][jh * 4 + 3] + bias[c + 3];
            *reinterpret_cast<float4*>(&C[(size_t)r * Nc + c]) = o;
        }
    }
}

__global__ __launch_bounds__(256, 1)
void stoch_attn_vec(const float* __restrict__ q,
                    const float* __restrict__ k,
                    float* __restrict__ v,
                    const float* __restrict__ Wsig,
                    const float* __restrict__ bsig,
                    const float* __restrict__ temp)
{
    const int h = blockIdx.x;
    const int b = blockIdx.y;

    __shared__ float Ks[NN][68];
    __shared__ float Vs[NN][68];

    const int tid = threadIdx.x;
    const size_t head_off = ((size_t)b * NN) * DD + (size_t)h * HD;

    for (int f = tid; f < NN * 16; f += 256) {
        const int n = f >> 4, c = (f & 15) << 2;
        *reinterpret_cast<float4*>(&Ks[n][c]) =
            *reinterpret_cast<const float4*>(&k[head_off + (size_t)n * DD + c]);
        *reinterpret_cast<float4*>(&Vs[n][c]) =
            *reinterpret_cast<const float4*>(&v[head_off + (size_t)n * DD + c]);
    }
    __syncthreads();

    const int n = tid;
    if (n < NN) {
        const float* qrow = q + head_off + (size_t)n * DD;
        float qreg[64];
        #pragma unroll
        for (int d4 = 0; d4 < 16; ++d4)
            *reinterpret_cast<float4*>(&qreg[d4 * 4]) =
                *reinterpret_cast<const float4*>(&qrow[d4 * 4]);

        float sd = 0.f;
        #pragma unroll
        for (int d = 0; d < 64; ++d) sd = fmaf(qreg[d], Wsig[d], sd);
        sd += bsig[0];
        const float sp = fmaxf(sd, 0.f) + log1pf(expf(-fabsf(sd)));
        const float st = (sp + 1e-3f) * temp[0];
        const float inv_denom = 1.0f / (2.0f * st * st);

        const int ry = n / 14, rx = n - 14 * (n / 14);

        float ctx[64];
        #pragma unroll
        for (int d = 0; d < 64; ++d) ctx[d] = 0.f;
        float mcur = 0.f, ssum = 0.f;

        int jy = 0, jx = 0;
        for (int j = 0; j < NN; ++j) {
            float s0 = 0.f, s1 = 0.f, s2 = 0.f, s3 = 0.f;
            #pragma unroll
            for (int d4 = 0; d4 < 16; ++d4) {
                const float4 kv = *reinterpret_cast<const float4*>(&Ks[j][d4 * 4]);
                s0 = fmaf(qreg[d4 * 4 + 0], kv.x, s0);
                s1 = fmaf(qreg[d4 * 4 + 1], kv.y, s1);
                s2 = fmaf(qreg[d4 * 4 + 2], kv.z, s2);
                s3 = fmaf(qreg[d4 * 4 + 3], kv.w, s3);
            }
            const float s = ((s0 + s1) + (s2 + s3)) * 0.125f;
            const int idy = ry - jy, idx = rx - jx;
            const float d2 = (float)(idy * idy + idx * idx);
            const float val = expf(-d2 * inv_denom) * s;
            if (val > mcur + 8.0f) {
                const float scale = expf(mcur - val);
                ssum *= scale;
                #pragma unroll
                for (int d = 0; d < 64; ++d) ctx[d] *= scale;
                mcur = val;
            }
            const float p = expf(val - mcur);
            ssum += p;
            #pragma unroll
            for (int d4 = 0; d4 < 16; ++d4) {
                const float4 vv = *reinterpret_cast<const float4*>(&Vs[j][d4 * 4]);
                ctx[d4 * 4 + 0] = fmaf(p, vv.x, ctx[d4 * 4 + 0]);
                ctx[d4 * 4 + 1] = fmaf(p, vv.y, ctx[d4 * 4 + 1]);
                ctx[d4 * 4 + 2] = fmaf(p, vv.z, ctx[d4 * 4 + 2]);
                ctx[d4 * 4 + 3] = fmaf(p, vv.w, ctx[d4 * 4 + 3]);
            }
            if (++jx == 14) { jx = 0; ++jy; }
        }

        const float inv = 1.0f / ssum;
        #pragma unroll
        for (int d4 = 0; d4 < 16; ++d4) {
            float4 o;
            o.x = ctx[d4 * 4 + 0] * inv;
            o.y = ctx[d4 * 4 + 1] * inv;
            o.z = ctx[d4 * 4 + 2] * inv;
            o.w = ctx[d4 * 4 + 3] * inv;
            *reinterpret_cast<float4*>(&v[head_off + (size_t)n * DD + d4 * 4]) = o;
        }
    }
}

// ---------------------------------------------------------------------------
extern "C" void kernel_launch(void* const* d_in, const int* in_sizes, int n_in,
                              void* d_out, int out_size, void* d_ws, size_t ws_size,
                              hipStream_t stream) {
    const float* hidden = (const float*)d_in[0];
    const float* temp   = (const float*)d_in[1];
    const float* Wq     = (const float*)d_in[2];
    const float* bq     = (const float*)d_in[3];
    const float* Wk     = (const float*)d_in[4];
    const float* bk     = (const float*)d_in[5];
    const float* Wv     = (const float*)d_in[6];
    const float* bv     = (const float*)d_in[7];
    const float* Wo     = (const float*)d_in[8];
    const float* bo     = (const float*)d_in[9];
    const float* Wsig   = (const float*)d_in[10];
    const float* bsig   = (const float*)d_in[11];
    float* out = (float*)d_out;

    const size_t A_ELEMS = (size_t)MM * DD;        // 9,633,792
    const size_t REQ_MFMA = A_ELEMS * 2 * 2        // Ahi/Alo (bf16)
                          + (size_t)4 * WE * 2 * 2 // WThi/WTlo (4 weights)
                          + A_ELEMS * 4 * 3;       // q/k/v fp32  => ~156 MB

    if (ws_size >= REQ_MFMA) {
        // ---------- PATH A: split-bf16 MFMA ----------
        unsigned char* p = (unsigned char*)d_ws;
        unsigned short* Ahi  = (unsigned short*)p; p += A_ELEMS * 2;
        unsigned short* Alo  = (unsigned short*)p; p += A_ELEMS * 2;
        unsigned short* WThi = (unsigned short*)p; p += (size_t)4 * WE * 2;
        unsigned short* WTlo = (unsigned short*)p; p += (size_t)4 * WE * 2;
        float* qbuf = (float*)p; p += A_ELEMS * 4;
        float* kbuf = (float*)p; p += A_ELEMS * 4;
        float* vbuf = (float*)p;
        // ctx aliases Ahi/Alo (dead after QKV GEMM; stream-ordered)
        unsigned short* ctxhi = Ahi;
        unsigned short* ctxlo = Alo;

        split_kernel<<<2048, 256, 0, stream>>>(hidden, Ahi, Alo, (int)(A_ELEMS / 4));
        wtrans_kernel<<<dim3(24, 24, 4), 256, 0, stream>>>(Wq, Wk, Wv, Wo, WThi, WTlo);

        gemm_mfma_kernel<<<dim3(MM / 128, DD / 128, 3), 256, 0, stream>>>(
            Ahi, Alo,
            WThi + 0 * (size_t)WE, WTlo + 0 * (size_t)WE, bq, qbuf,
            WThi + 1 * (size_t)WE, WTlo + 1 * (size_t)WE, bk, kbuf,
            WThi + 2 * (size_t)WE, WTlo + 2 * (size_t)WE, bv, vbuf);

        stoch_attn_mfma<<<dim3(HH, BB), 256, 0, stream>>>(
            qbuf, kbuf, vbuf, ctxhi, ctxlo, Wsig, bsig, temp);

        gemm_mfma_kernel<<<dim3(MM / 128, DD / 128, 1), 256, 0, stream>>>(
            ctxhi, ctxlo,
            WThi + 3 * (size_t)WE, WTlo + 3 * (size_t)WE, bo, out,
            WThi + 3 * (size_t)WE, WTlo + 3 * (size_t)WE, bo, out,
            WThi + 3 * (size_t)WE, WTlo + 3 * (size_t)WE, bo, out);
    } else {
        // ---------- PATH B: fp32 vector (needs only q/k/v = ~110 MB) ----------
        float* qbuf = (float*)d_ws;
        float* kbuf = qbuf + A_ELEMS;
        float* vbuf = kbuf + A_ELEMS;   // ctx overwrites vbuf

        dim3 g1(MM / 128, DD / 128, 3);
        gemm_bias_kernel<<<g1, 256, 0, stream>>>(hidden,
                                                 Wq, bq, qbuf,
                                                 Wk, bk, kbuf,
                                                 Wv, bv, vbuf);

        stoch_attn_vec<<<dim3(HH, BB), 256, 0, stream>>>(
            qbuf, kbuf, vbuf, Wsig, bsig, temp);

        dim3 g3(MM / 128, DD / 128, 1);
        gemm_bias_kernel<<<g3, 256, 0, stream>>>(vbuf,
                                                 Wo, bo, out,
                                                 Wo, bo, out,
                                                 Wo, bo, out);
    }
}